// Round 1
// baseline (171.384 us; speedup 1.0000x reference)
//
#include <hip/hip_runtime.h>

// GraphConv B=256,N=512,D=6,F=128,MAX_DEG=6.
// R6 post-mortem: LDS-resident gather (k1) landed at ~46us but counters show
// NO saturated pipe (VALU 13%, HBM 20%, occupancy 17%, conflicts 3.7%) ->
// latency-bound at 2 blocks/CU (LDS 76KB). R7: halve slice to 16 floats,
// XOR-swizzled float4 LDS layout (no pad) -> 39KB LDS -> 4 blocks/CU,
// ds_read_b128 gather (half the LDS instruction count), packed b32 nbr-id
// reads. Grid 2048 = 256 molecules x 8 slices. k2 (MFMA GEMM) unchanged.

typedef short bf16x8 __attribute__((ext_vector_type(8)));
typedef float f32x4  __attribute__((ext_vector_type(4)));
typedef unsigned short ushort_t;
typedef unsigned int uint_t;

constexpr int Nn = 512;
constexpr int Ff = 128;
constexpr int BN = 256 * 512;             // 131072 atoms

// ws layout (bytes)
constexpr size_t WS_GC     = 0;                         // i32 [6] (+pad to 256)
constexpr size_t WS_REGION = 256;                       // i32 [6][BN]
constexpr size_t WS_WT     = 256 + (size_t)6 * BN * 4;  // bf16 [6][128][128]
constexpr size_t WS_SUMMED = WS_WT + 196608;            // bf16 [BN][128]
constexpr size_t WS_NEEDED = WS_SUMMED + (size_t)BN * 128 * 2;   // ~36.9 MB

__device__ inline ushort_t f2bf(float f) {              // round-to-nearest-even
    uint_t u = __float_as_uint(f);
    return (ushort_t)((u + 0x7FFFu + ((u >> 16) & 1u)) >> 16);
}

__device__ inline bool detect_is64(const int* edges32) {
    // int64 edges: odd dwords are sign-extension words in {0,-1}.
    int probe = edges32[2 * (threadIdx.x & 63) + 1];
    return __any(probe > 0) == 0;
}

// ---------------- K1: molecule-resident LDS gather ----------------
// grid: 2048 blocks = 256 molecules x 8 column-slices of 16 floats.
// LDS ~39KB -> 4 blocks/CU (16 waves) vs old 76KB/2 blocks (8 waves).
__global__ __launch_bounds__(256, 4)
void k1_pre(const float* __restrict__ atoms,
            const int*   __restrict__ edges32,
            const float* __restrict__ W,
            int* __restrict__ gcnt,
            int* __restrict__ region,
            ushort_t* __restrict__ Wt,
            ushort_t* __restrict__ summed) {
    const int tid   = threadIdx.x;
    const int mol   = blockIdx.x >> 3;
    const int slice = blockIdx.x & 7;
    const bool is64 = detect_is64(edges32);   // convergent

    // XOR-swizzled atom slice: logical (row, q4) lives at A4[row*4 + (q4 ^ (row&3))].
    // Write side permutes within a 64B row-chunk (coalescing unchanged);
    // read side spreads same-column reads of consecutive rows over 4 bank quads.
    __shared__ float4   A4[Nn * 4];              // 32768 B
    __shared__ ushort_t nbp[Nn * 6];             // 6144 B (packed nbr ids)
    __shared__ int      hist[6], base_sh[6];

    // W -> bf16 transposed [d][n][k]: first 384 blocks, 256 elts each
    if (blockIdx.x < 384) {
        int linear = blockIdx.x * 256 + tid;          // [d][k][n] linear, 98304
        int d = linear >> 14, rem = linear & 16383;
        int k = rem >> 7, n = rem & 127;
        Wt[d * 16384 + n * 128 + k] = f2bf(W[linear]);
    }

    // ---- stage edges (packed u16; 0xFFFF = invalid) ----
    {
        const size_t ebase = (size_t)mol * (Nn * 6);
        for (int i = tid; i < Nn * 6; i += 256) {
            int e = is64 ? edges32[(ebase + i) * 2] : edges32[ebase + i];
            nbp[i] = (ushort_t)(e >= 0 ? e : 0xFFFF);
        }
    }

    // ---- stage atom slice: 512 rows x 16 floats, coalesced (swizzle is
    //      within each row's 64B -> global access pattern unchanged) ----
    {
        const float4* gsrc = (const float4*)(atoms + (size_t)mol * (Nn * Ff) + slice * 16);
        #pragma unroll
        for (int it = 0; it < 8; it++) {
            int idx = tid + it * 256;         // float4 index in slice (2048 total)
            int row = idx >> 2, q = idx & 3;
            float4 v = gsrc[row * 32 + q];    // row stride 128 floats = 32 float4
            A4[row * 4 + (q ^ (row & 3))] = v;
        }
    }
    __syncthreads();

    // ---- slice 0: degree-scatter via LDS-atomic ranks ----
    if (slice == 0) {
        if (tid < 6) hist[tid] = 0;
        __syncthreads();
        int dg[2], rk[2];
        #pragma unroll
        for (int s = 0; s < 2; s++) {
            int row = tid + s * 256;
            int dd = 0;
            #pragma unroll
            for (int j = 0; j < 6; j++) dd += (nbp[row * 6 + j] != 0xFFFF) ? 1 : 0;
            dg[s] = dd;
            rk[s] = atomicAdd(&hist[dd], 1);
        }
        __syncthreads();
        if (tid < 6) base_sh[tid] = atomicAdd(&gcnt[tid], hist[tid]);
        __syncthreads();
        #pragma unroll
        for (int s = 0; s < 2; s++)
            region[dg[s] * BN + base_sh[dg[s]] + rk[s]] = mol * Nn + tid + s * 256;
    }

    // ---- gather-sum from LDS: 2 threads/row x 8 floats (2x b128), 4 rounds ----
    const int h = tid & 1, qb = 2 * (tid & 1);
    const uint_t* np = (const uint_t*)nbp;
    #pragma unroll
    for (int rd = 0; rd < 4; rd++) {
        const int row = rd * 128 + (tid >> 1);
        // neighbor ids: 3x ds_read_b32 instead of 6x ds_read_u16
        uint_t u0 = np[row * 3], u1 = np[row * 3 + 1], u2 = np[row * 3 + 2];
        int e[6] = { (int)(u0 & 0xFFFFu), (int)(u0 >> 16),
                     (int)(u1 & 0xFFFFu), (int)(u1 >> 16),
                     (int)(u2 & 0xFFFFu), (int)(u2 >> 16) };
        int sb = row * 4 + (qb ^ (row & 3));
        float4 a0 = A4[sb];                   // logical floats [h*8 .. h*8+3]
        float4 a1 = A4[sb ^ 1];               // logical floats [h*8+4 .. h*8+7]
        #pragma unroll
        for (int j = 0; j < 6; j++) {
            if (e[j] != 0xFFFF) {
                int nb = e[j] * 4 + (qb ^ (e[j] & 3));
                float4 v0 = A4[nb];
                float4 v1 = A4[nb ^ 1];
                a0.x += v0.x; a0.y += v0.y; a0.z += v0.z; a0.w += v0.w;
                a1.x += v1.x; a1.y += v1.y; a1.z += v1.z; a1.w += v1.w;
            }
        }
        uint4 o;
        o.x = (uint_t)f2bf(a0.x) | ((uint_t)f2bf(a0.y) << 16);
        o.y = (uint_t)f2bf(a0.z) | ((uint_t)f2bf(a0.w) << 16);
        o.z = (uint_t)f2bf(a1.x) | ((uint_t)f2bf(a1.y) << 16);
        o.w = (uint_t)f2bf(a1.z) | ((uint_t)f2bf(a1.w) << 16);
        *(uint4*)(summed + (size_t)(mol * Nn + row) * Ff + slice * 16 + h * 8) = o;
    }
}

// ---------------- K2: GEMM (B in LDS, A-frags direct from global) ----------------
__global__ __launch_bounds__(256, 4)
void k2_gemm(const ushort_t* __restrict__ summed,
             const float*    __restrict__ bias,
             const ushort_t* __restrict__ Wt,
             const int*      __restrict__ region,
             const int*      __restrict__ gcnt,
             float*          __restrict__ out) {
    // map flat block id -> (degree d, tile t)
    int cnts[6];
    #pragma unroll
    for (int dd = 0; dd < 6; dd++) cnts[dd] = gcnt[dd];
    const int bid = blockIdx.x;
    int d = -1, t = 0, accum = 0;
    #pragma unroll
    for (int dd = 0; dd < 6; dd++) {
        int tl = (cnts[dd] + 127) >> 7;
        if (d < 0 && bid < accum + tl) { d = dd; t = bid - accum; }
        accum += tl;
    }
    if (d < 0) return;
    const int count = cnts[d];
    const int m0 = t * 128;
    const int nrows = min(128, count - m0);

    __shared__ __attribute__((aligned(16))) ushort_t Bsh[128 * 136];
    __shared__ int ids[128];

    const int tid = threadIdx.x;
    if (tid < 128) {
        int idx = m0 + tid;
        if (idx >= count) idx = count - 1;     // clamp; stores masked by nrows
        ids[tid] = region[d * BN + idx];
    }
    // stage B: Wt[d] bf16 [n][k] -> LDS pad 136
    {
        const uint4* Wg = (const uint4*)(Wt + (size_t)d * 16384);
        #pragma unroll
        for (int i = 0; i < 8; i++) {
            int idx = tid + i * 256;           // uint4 chunks, 2048 total
            int n = idx >> 4, c = idx & 15;
            *(uint4*)&Bsh[n * 136 + c * 8] = Wg[idx];
        }
    }
    __syncthreads();

    const int lane = tid & 63, w = tid >> 6;
    const int mrow = w * 32;
    const int kq = lane >> 4;                  // 0..3
    const int ml = lane & 15;

    // A-frags directly from global summed (MFMA A layout: m=ml, k=k0*32+kq*8..)
    bf16x8 af[2][4];
    #pragma unroll
    for (int mt = 0; mt < 2; mt++) {
        const int row = ids[mrow + mt * 16 + ml];
        const bf16x8* sp = (const bf16x8*)(summed + (size_t)row * Ff + kq * 8);
        #pragma unroll
        for (int k0 = 0; k0 < 4; k0++) af[mt][k0] = sp[k0 * 4];   // +32 elts
    }

    #pragma unroll
    for (int nt = 0; nt < 8; nt++) {
        bf16x8 bfr[4];
        #pragma unroll
        for (int k0 = 0; k0 < 4; k0++)
            bfr[k0] = *(const bf16x8*)&Bsh[(nt * 16 + ml) * 136 + k0 * 32 + kq * 8];
        f32x4 c0 = {0.f, 0.f, 0.f, 0.f}, c1 = {0.f, 0.f, 0.f, 0.f};
        #pragma unroll
        for (int k0 = 0; k0 < 4; k0++) {
            c0 = __builtin_amdgcn_mfma_f32_16x16x32_bf16(af[0][k0], bfr[k0], c0, 0, 0, 0);
            c1 = __builtin_amdgcn_mfma_f32_16x16x32_bf16(af[1][k0], bfr[k0], c1, 0, 0, 0);
        }
        const int col = nt * 16 + ml;
        const float bcol = bias[d * Ff + col];
        #pragma unroll
        for (int mt = 0; mt < 2; mt++) {
            f32x4 cc = mt ? c1 : c0;
            #pragma unroll
            for (int reg = 0; reg < 4; reg++) {
                int rl = mrow + mt * 16 + kq * 4 + reg;    // C/D: row=(lane>>4)*4+reg
                if (rl < nrows) {
                    float v = cc[reg] + bcol;
                    out[(size_t)ids[rl] * Ff + col] = v > 0.f ? v : 0.f;
                }
            }
        }
    }
}

// ---------------- fallback (round-1 kernel) if ws too small ----------------
__global__ __launch_bounds__(128, 2)
void graphconv_fallback(const float* __restrict__ atoms,
                        const int* __restrict__ edges_raw,
                        const float* __restrict__ W,
                        const float* __restrict__ bias,
                        float* __restrict__ out) {
    const int tid = threadIdx.x;
    const int d = blockIdx.x % 6;
    const int k = blockIdx.x / 6;
    const int a0 = k * 256;
    __shared__ int eds[256 * 6];
    __shared__ int list[256];
    __shared__ int cnt;
    __shared__ float sv[2][Ff];
    bool is64;
    { int v = edges_raw[2 * (tid & 63) + 1]; is64 = (__ballot(v > 0) == 0ull); }
    if (!is64) { for (int i = tid; i < 256 * 6; i += 128) eds[i] = edges_raw[a0 * 6 + i]; }
    else       { for (int i = tid; i < 256 * 6; i += 128) eds[i] = edges_raw[2 * (a0 * 6 + i)]; }
    if (tid == 0) cnt = 0;
    __syncthreads();
    for (int i = tid; i < 256; i += 128) {
        int deg = 0;
        #pragma unroll
        for (int j = 0; j < 6; j++) deg += (eds[i * 6 + j] != -1) ? 1 : 0;
        if (deg == d) { int p = atomicAdd(&cnt, 1); list[p] = i; }
    }
    float Wreg[Ff];
    { const float* Wd = W + (size_t)d * Ff * Ff;
      #pragma unroll
      for (int f = 0; f < Ff; f++) Wreg[f] = Wd[f * Ff + tid]; }
    const float breg = bias[d * Ff + tid];
    __syncthreads();
    const int n = cnt;
    const float* batch_atoms = atoms + (size_t)(a0 / Nn) * Nn * Ff;
    const int row0 = a0 % Nn;
    for (int ii = 0; ii < n; ii++) {
        const int i = list[ii];
        float s = batch_atoms[(row0 + i) * Ff + tid];
        #pragma unroll
        for (int j = 0; j < 6; j++) {
            int e = eds[i * 6 + j];
            if (e != -1) s += batch_atoms[e * Ff + tid];
        }
        float* buf = sv[ii & 1];
        buf[tid] = s;
        __syncthreads();
        float acc = breg;
        const float4* sv4 = (const float4*)buf;
        #pragma unroll
        for (int fc = 0; fc < Ff / 4; fc++) {
            float4 x = sv4[fc];
            acc = fmaf(x.x, Wreg[4 * fc + 0], acc);
            acc = fmaf(x.y, Wreg[4 * fc + 1], acc);
            acc = fmaf(x.z, Wreg[4 * fc + 2], acc);
            acc = fmaf(x.w, Wreg[4 * fc + 3], acc);
        }
        out[(size_t)(a0 + i) * Ff + tid] = fmaxf(acc, 0.0f);
    }
}

extern "C" void kernel_launch(void* const* d_in, const int* in_sizes, int n_in,
                              void* d_out, int out_size, void* d_ws, size_t ws_size,
                              hipStream_t stream) {
    const float* atoms = (const float*)d_in[0];
    const int*   edges = (const int*)d_in[1];
    const float* W     = (const float*)d_in[2];
    const float* bias  = (const float*)d_in[3];
    float*       outp  = (float*)d_out;

    if (ws_size >= WS_NEEDED) {
        char* ws = (char*)d_ws;
        int*      gcnt   = (int*)(ws + WS_GC);
        int*      region = (int*)(ws + WS_REGION);
        ushort_t* Wt     = (ushort_t*)(ws + WS_WT);
        ushort_t* summed = (ushort_t*)(ws + WS_SUMMED);

        hipMemsetAsync(gcnt, 0, 32, stream);
        k1_pre<<<2048, 256, 0, stream>>>(atoms, edges, W, gcnt, region, Wt, summed);
        k2_gemm<<<1030, 256, 0, stream>>>(summed, bias, Wt, region, gcnt, outp);
    } else {
        graphconv_fallback<<<3072, 128, 0, stream>>>(atoms, edges, W, bias, outp);
    }
}

// Round 3
// 156.433 us; speedup vs baseline: 1.0956x; 1.0956x over previous
//
#include <hip/hip_runtime.h>

// GraphConv B=256,N=512,D=6,F=128,MAX_DEG=6.
// R8 post-mortem: LDS OOB in phase-B W staging (idx>>3 mapped 1024 chunks to
// 128 rows; Wsh is 64 rows x 16 chunks) -> wrote past the LDS aperture ->
// abort. R9: fix indexing (idx>>4 / idx&15); all other structure unchanged.
// Fused design: 1 molecule/block (256 x 512thr). summed lives in LDS only;
// edges read once per molecule (regs, 1 row/thread); per-molecule degree
// grouping in LDS; MFMA epilogue stages W-halves into reused scratch LDS.
// k0 pre-transposes W -> bf16 [d][n][k]. HBM ideal ~140MB => ~22us floor.

typedef short bf16x8 __attribute__((ext_vector_type(8)));
typedef float f32x4  __attribute__((ext_vector_type(4)));
typedef unsigned short ushort_t;
typedef unsigned int uint_t;

constexpr int Nn = 512;
constexpr int Ff = 128;

// ws: Wt bf16 [6][128][128] ([d][n][k])
constexpr size_t WS_NEEDED = 196608;

__device__ inline ushort_t f2bf(float f) {              // round-to-nearest-even
    uint_t u = __float_as_uint(f);
    return (ushort_t)((u + 0x7FFFu + ((u >> 16) & 1u)) >> 16);
}

__device__ inline bool detect_is64(const int* edges32) {
    // int64 edges: odd dwords are sign-extension words in {0,-1}.
    int probe = edges32[2 * (threadIdx.x & 63) + 1];
    return __any(probe > 0) == 0;
}

// ---------------- k0: W fp32 [d][k][n] -> Wt bf16 [d][n][k] ----------------
__global__ __launch_bounds__(1024)
void k0_wt(const float* __restrict__ W, ushort_t* __restrict__ Wt) {
    int L = blockIdx.x * 1024 + threadIdx.x;     // 96 blocks x 1024 = 98304
    int d = L >> 14, rem = L & 16383;
    int n = rem >> 7, k = rem & 127;
    Wt[L] = f2bf(W[(d << 14) + (k << 7) + n]);   // coalesced write, strided read (W is 384KB, L2)
}

// ---------------- fused: one molecule per block ----------------
// 512 threads = 8 waves; thread t owns row t. LDS 157.7KB -> 1 block/CU.
__global__ __launch_bounds__(512, 2)
void k_fused(const float* __restrict__ atoms,
             const int*   __restrict__ edges32,
             const ushort_t* __restrict__ Wt,
             const float* __restrict__ bias,
             float* __restrict__ out) {
    const int tid = threadIdx.x;
    const int mol = blockIdx.x;
    const bool is64 = detect_is64(edges32);      // convergent

    __shared__ ushort_t summed[Nn * 136];        // 139264 B (pad 136: granules/row=17, coprime 8)
    __shared__ float4   scratch4[1088];          // 17408 B: phase-A abuf (1026 used) / phase-B Wsh
    __shared__ ushort_t rlist[Nn];               // 1024 B: row ids grouped by degree
    __shared__ int hist[6], base_sh[8];

    float4*   abuf4 = scratch4;                  // [row 0..512][2 granules], swizzled
    ushort_t* Wsh   = (ushort_t*)scratch4;       // [64][136] bf16 in phase B

    // --- prefetch atom slice 0 (floats 0..7 of all rows) into regs ---
    const float4* gsrc = (const float4*)(atoms + (size_t)mol * (Nn * Ff));
    // 1024 float4/slice; thread handles idx {tid, tid+512}: row=idx>>1, c=idx&1
    float4 pf0 = gsrc[(tid >> 1) * 32 + (tid & 1)];
    float4 pf1 = gsrc[((tid + 512) >> 1) * 32 + (tid & 1)];

    // --- phase 0: edges for own row (held in regs), degree ranks ---
    int e_[6];
    {
        const size_t eb = (size_t)mol * (Nn * 6) + (size_t)tid * 6;
        #pragma unroll
        for (int j = 0; j < 6; j++)
            e_[j] = is64 ? edges32[(eb + j) * 2] : edges32[eb + j];
    }
    int deg = 0;
    #pragma unroll
    for (int j = 0; j < 6; j++) deg += (e_[j] >= 0) ? 1 : 0;
    if (deg > 5) deg = 5;                        // ref guarantees <=5; guard OOB
    int er[6];                                   // invalid -> row Nn (zero row): branchless gather
    #pragma unroll
    for (int j = 0; j < 6; j++) er[j] = (e_[j] >= 0) ? e_[j] : Nn;

    if (tid < 6) hist[tid] = 0;
    if (tid < 2) abuf4[2 * Nn + tid] = make_float4(0.f, 0.f, 0.f, 0.f);  // zero row
    __syncthreads();
    int rk = atomicAdd(&hist[deg], 1);
    __syncthreads();
    if (tid == 0) {
        int acc = 0;
        #pragma unroll
        for (int d = 0; d < 6; d++) { base_sh[d] = acc; acc += hist[d]; }
    }
    __syncthreads();
    rlist[base_sh[deg] + rk] = (ushort_t)tid;

    // write abuf slice 0. Swizzle: granule c of row r at [2r + (c ^ ((r>>2)&1))]
    // -> any 64-lane b128 access (rows consecutive OR random) spreads over all
    //    8 bank-quads.
    {
        int r0 = tid >> 1, c0 = tid & 1;
        abuf4[2 * r0 + (c0 ^ ((r0 >> 2) & 1))] = pf0;
        int r1 = (tid + 512) >> 1;
        abuf4[2 * r1 + (c0 ^ ((r1 >> 2) & 1))] = pf1;
    }
    __syncthreads();

    // --- phase A: 16 slices of 8 floats, T14 prefetch pipeline ---
    const int sg = (tid >> 2) & 1;               // own-row swizzle bit
    for (int s = 0; s < 16; s++) {
        if (s < 15) {                            // issue next-slice loads early
            pf0 = gsrc[(tid >> 1) * 32 + (s + 1) * 2 + (tid & 1)];
            pf1 = gsrc[((tid + 512) >> 1) * 32 + (s + 1) * 2 + (tid & 1)];
        }
        float4 a0 = abuf4[2 * tid + sg];         // self, floats [s*8 .. s*8+3]
        float4 a1 = abuf4[2 * tid + (1 ^ sg)];   //        floats [s*8+4 .. +7]
        #pragma unroll
        for (int j = 0; j < 6; j++) {            // branchless: er==Nn adds zeros
            int e = er[j];
            int se = (e >> 2) & 1;
            float4 v0 = abuf4[2 * e + se];
            float4 v1 = abuf4[2 * e + (1 ^ se)];
            a0.x += v0.x; a0.y += v0.y; a0.z += v0.z; a0.w += v0.w;
            a1.x += v1.x; a1.y += v1.y; a1.z += v1.z; a1.w += v1.w;
        }
        uint4 o;
        o.x = (uint_t)f2bf(a0.x) | ((uint_t)f2bf(a0.y) << 16);
        o.y = (uint_t)f2bf(a0.z) | ((uint_t)f2bf(a0.w) << 16);
        o.z = (uint_t)f2bf(a1.x) | ((uint_t)f2bf(a1.y) << 16);
        o.w = (uint_t)f2bf(a1.z) | ((uint_t)f2bf(a1.w) << 16);
        *(uint4*)&summed[tid * 136 + s * 8] = o;
        __syncthreads();                         // all abuf reads done
        if (s < 15) {                            // land prefetch (vmcnt by compiler)
            int r0 = tid >> 1, c0 = tid & 1;
            abuf4[2 * r0 + (c0 ^ ((r0 >> 2) & 1))] = pf0;
            int r1 = (tid + 512) >> 1;
            abuf4[2 * r1 + (c0 ^ ((r1 >> 2) & 1))] = pf1;
            __syncthreads();                     // abuf ready for next gather
        }
    }
    // (s=15 iteration ended with __syncthreads: summed complete, abuf free)

    // --- phase B: per-degree MFMA tiles, W halves staged into scratch ---
    const int lane = tid & 63, wid = tid >> 6;
    const int kq = lane >> 4, ml = lane & 15;

    for (int d = 0; d < 6; d++) {
        const int cb = base_sh[d], cn = hist[d];
        const int Td = (cn + 15) >> 4;
        const uint4* wg = (const uint4*)(Wt + (size_t)d * 16384);
        for (int half = 0; half < 2; half++) {
            // stage Wsh [64][136] <- Wt[d][half*64+n][k]: 1024 uint4 (64 rows
            // x 16 chunks), coalesced.  (R8 bug: idx>>3 mapped to 128 rows ->
            // LDS OOB; correct is idx>>4 / idx&15.)
            {
                int i0 = tid;
                int n = i0 >> 4, c = i0 & 15;
                *(uint4*)&Wsh[n * 136 + c * 8] = wg[half * 1024 + i0];
                int i1 = tid + 512;
                n = i1 >> 4; c = i1 & 15;
                *(uint4*)&Wsh[n * 136 + c * 8] = wg[half * 1024 + i1];
            }
            __syncthreads();
            const int items = Td * 2;            // (tile, nt-pair) work items
            for (int it = wid; it < items; it += 8) {
                const int ti = it >> 1, nh = it & 1;
                int lidx = ti * 16 + ml;
                int cl = (lidx < cn) ? lidx : cn - 1;   // clamp; stores masked
                int row = rlist[cb + cl];
                bf16x8 af[4];                    // A: m=ml, k=kq*8+k0*32
                #pragma unroll
                for (int k0 = 0; k0 < 4; k0++)
                    af[k0] = *(const bf16x8*)&summed[row * 136 + kq * 8 + k0 * 32];
                int orw[4];                      // C/D rows: kq*4+reg
                #pragma unroll
                for (int r = 0; r < 4; r++) {
                    int li = ti * 16 + kq * 4 + r;
                    orw[r] = (li < cn) ? (int)rlist[cb + li] : -1;
                }
                #pragma unroll
                for (int n2 = 0; n2 < 2; n2++) {
                    const int nt = nh * 2 + n2;
                    bf16x8 bfr[4];               // B: n=ml, k=kq*8+k0*32
                    #pragma unroll
                    for (int k0 = 0; k0 < 4; k0++)
                        bfr[k0] = *(const bf16x8*)&Wsh[(nt * 16 + ml) * 136 + k0 * 32 + kq * 8];
                    f32x4 c = {0.f, 0.f, 0.f, 0.f};
                    #pragma unroll
                    for (int k0 = 0; k0 < 4; k0++)
                        c = __builtin_amdgcn_mfma_f32_16x16x32_bf16(af[k0], bfr[k0], c, 0, 0, 0);
                    const int col = half * 64 + nt * 16 + ml;
                    const float bc = bias[d * Ff + col];
                    #pragma unroll
                    for (int r = 0; r < 4; r++) {
                        if (orw[r] >= 0) {
                            float v = c[r] + bc;
                            out[((size_t)mol * Nn + orw[r]) * Ff + col] = v > 0.f ? v : 0.f;
                        }
                    }
                }
            }
            __syncthreads();                     // before Wsh overwrite
        }
    }
}

// ---------------- fallback (round-1 kernel) if ws too small ----------------
__global__ __launch_bounds__(128, 2)
void graphconv_fallback(const float* __restrict__ atoms,
                        const int* __restrict__ edges_raw,
                        const float* __restrict__ W,
                        const float* __restrict__ bias,
                        float* __restrict__ out) {
    const int tid = threadIdx.x;
    const int d = blockIdx.x % 6;
    const int k = blockIdx.x / 6;
    const int a0 = k * 256;
    __shared__ int eds[256 * 6];
    __shared__ int list[256];
    __shared__ int cnt;
    __shared__ float sv[2][Ff];
    bool is64;
    { int v = edges_raw[2 * (tid & 63) + 1]; is64 = (__ballot(v > 0) == 0ull); }
    if (!is64) { for (int i = tid; i < 256 * 6; i += 128) eds[i] = edges_raw[a0 * 6 + i]; }
    else       { for (int i = tid; i < 256 * 6; i += 128) eds[i] = edges_raw[2 * (a0 * 6 + i)]; }
    if (tid == 0) cnt = 0;
    __syncthreads();
    for (int i = tid; i < 256; i += 128) {
        int deg = 0;
        #pragma unroll
        for (int j = 0; j < 6; j++) deg += (eds[i * 6 + j] != -1) ? 1 : 0;
        if (deg == d) { int p = atomicAdd(&cnt, 1); list[p] = i; }
    }
    float Wreg[Ff];
    { const float* Wd = W + (size_t)d * Ff * Ff;
      #pragma unroll
      for (int f = 0; f < Ff; f++) Wreg[f] = Wd[f * Ff + tid]; }
    const float breg = bias[d * Ff + tid];
    __syncthreads();
    const int n = cnt;
    const float* batch_atoms = atoms + (size_t)(a0 / Nn) * Nn * Ff;
    const int row0 = a0 % Nn;
    for (int ii = 0; ii < n; ii++) {
        const int i = list[ii];
        float s = batch_atoms[(row0 + i) * Ff + tid];
        #pragma unroll
        for (int j = 0; j < 6; j++) {
            int e = eds[i * 6 + j];
            if (e != -1) s += batch_atoms[e * Ff + tid];
        }
        float* buf = sv[ii & 1];
        buf[tid] = s;
        __syncthreads();
        float acc = breg;
        const float4* sv4 = (const float4*)buf;
        #pragma unroll
        for (int fc = 0; fc < Ff / 4; fc++) {
            float4 x = sv4[fc];
            acc = fmaf(x.x, Wreg[4 * fc + 0], acc);
            acc = fmaf(x.y, Wreg[4 * fc + 1], acc);
            acc = fmaf(x.z, Wreg[4 * fc + 2], acc);
            acc = fmaf(x.w, Wreg[4 * fc + 3], acc);
        }
        out[(size_t)(a0 + i) * Ff + tid] = fmaxf(acc, 0.0f);
    }
}

extern "C" void kernel_launch(void* const* d_in, const int* in_sizes, int n_in,
                              void* d_out, int out_size, void* d_ws, size_t ws_size,
                              hipStream_t stream) {
    const float* atoms = (const float*)d_in[0];
    const int*   edges = (const int*)d_in[1];
    const float* W     = (const float*)d_in[2];
    const float* bias  = (const float*)d_in[3];
    float*       outp  = (float*)d_out;

    if (ws_size >= WS_NEEDED) {
        ushort_t* Wt = (ushort_t*)d_ws;
        k0_wt<<<96, 1024, 0, stream>>>(W, Wt);
        k_fused<<<256, 512, 0, stream>>>(atoms, edges, Wt, bias, outp);
    } else {
        graphconv_fallback<<<3072, 128, 0, stream>>>(atoms, edges, W, bias, outp);
    }
}